// Round 1
// baseline (90.879 us; speedup 1.0000x reference)
//
#include <hip/hip_runtime.h>
#include <math.h>

#define NP 400
#define NV 204
#define STEP 20
#define HW 4096
#define BS 8

__global__ void zero_acc_kernel(float* acc) { acc[0] = 0.0f; }

__global__ __launch_bounds__(256) void get_loss_kernel(
    const float* __restrict__ pred_r,    // (8,4,4096)
    const float* __restrict__ pred_t,    // (8,3,4096)
    const float* __restrict__ pred_score,// (8,4096)
    const float* __restrict__ gt_r,      // (8,3,3)
    const float* __restrict__ gt_t,      // (8,3)
    const int*   __restrict__ cls_ids,   // (8,)
    const float* __restrict__ model_xyz, // (8,3,400)
    float* __restrict__ acc)
{
    const int v   = blockIdx.x;   // 0..203
    const int b   = blockIdx.y;   // 0..7
    const int tid = threadIdx.x;  // 0..255
    const int pix = v * STEP;

    __shared__ float s_gx[NP], s_gy[NP], s_gz[NP];
    __shared__ float s_part[4];

    // ---- per-batch scalars (uniform across block) ----
    const float g00 = gt_r[b*9+0], g01 = gt_r[b*9+1], g02 = gt_r[b*9+2];
    const float g10 = gt_r[b*9+3], g11 = gt_r[b*9+4], g12 = gt_r[b*9+5];
    const float g20 = gt_r[b*9+6], g21 = gt_r[b*9+7], g22 = gt_r[b*9+8];
    const float gtx = gt_t[b*3+0], gty = gt_t[b*3+1], gtz = gt_t[b*3+2];
    const int   cls = cls_ids[b];
    const bool  sym = (cls==12)||(cls==15)||(cls==18)||(cls==19)||(cls==20);
    const bool  valid = (cls+1 >= 1) && (cls+1 <= 30); // SELECT_ID = 1..30

    // ---- stage gt points in LDS ----
    const float* mb = model_xyz + (size_t)b * 3 * NP;
    for (int q = tid; q < NP; q += 256) {
        float mx = mb[q], my = mb[NP+q], mz = mb[2*NP+q];
        s_gx[q] = g00*mx + g01*my + g02*mz + gtx;
        s_gy[q] = g10*mx + g11*my + g12*mz + gty;
        s_gz[q] = g20*mx + g21*my + g22*mz + gtz;
    }

    // ---- quaternion -> rotation for this (b,v) ----
    float q0 = pred_r[((size_t)b*4+0)*HW + pix];
    float q1 = pred_r[((size_t)b*4+1)*HW + pix];
    float q2 = pred_r[((size_t)b*4+2)*HW + pix];
    float q3 = pred_r[((size_t)b*4+3)*HW + pix];
    {
        float inv = 1.0f / sqrtf(q0*q0 + q1*q1 + q2*q2 + q3*q3);
        q0 *= inv; q1 *= inv; q2 *= inv; q3 *= inv;
    }
    const float R00 = 1.0f - 2.0f*(q2*q2 + q3*q3);
    const float R01 = 2.0f*q1*q2 - 2.0f*q0*q3;
    const float R02 = 2.0f*q0*q2 + 2.0f*q1*q3;
    const float R10 = 2.0f*q1*q2 + 2.0f*q3*q0;
    const float R11 = 1.0f - 2.0f*(q1*q1 + q3*q3);
    const float R12 = -2.0f*q0*q1 + 2.0f*q2*q3;
    const float R20 = -2.0f*q0*q2 + 2.0f*q1*q3;
    const float R21 = 2.0f*q0*q1 + 2.0f*q2*q3;
    const float R22 = 1.0f - 2.0f*(q1*q1 + q2*q2);

    const float ptx = pred_t[((size_t)b*3+0)*HW + pix];
    const float pty = pred_t[((size_t)b*3+1)*HW + pix];
    const float ptz = pred_t[((size_t)b*3+2)*HW + pix];

    __syncthreads();

    // ---- per-point distances ----
    float local = 0.0f;
    for (int p = tid; p < NP; p += 256) {
        float mx = mb[p], my = mb[NP+p], mz = mb[2*NP+p];
        float px = R00*mx + R01*my + R02*mz + ptx;
        float py = R10*mx + R11*my + R12*mz + pty;
        float pz = R20*mx + R21*my + R22*mz + ptz;
        float d2;
        if (sym) {
            // ADD-S: min over q of squared distance (exact same min as
            // pn+gn-2*cross form, better numerics). LDS reads are
            // wave-uniform -> broadcast, conflict-free.
            float m = 3.4e38f;
            #pragma unroll 4
            for (int q = 0; q < NP; ++q) {
                float dx = px - s_gx[q];
                float dy = py - s_gy[q];
                float dz = pz - s_gz[q];
                float d = dx*dx + dy*dy + dz*dz;
                m = fminf(m, d);
            }
            d2 = m;
        } else {
            float dx = px - s_gx[p];
            float dy = py - s_gy[p];
            float dz = pz - s_gz[p];
            d2 = dx*dx + dy*dy + dz*dz;
        }
        local += sqrtf(d2);
    }

    // ---- block reduction (4 waves of 64) ----
    #pragma unroll
    for (int off = 32; off > 0; off >>= 1)
        local += __shfl_down(local, off, 64);
    const int wave = tid >> 6;
    if ((tid & 63) == 0) s_part[wave] = local;
    __syncthreads();
    if (tid == 0) {
        float tot  = s_part[0] + s_part[1] + s_part[2] + s_part[3];
        float mean = tot * (1.0f / NP);               // add_ij[b,v]
        float ps   = pred_score[(size_t)b*HW + pix];
        float c = 0.0f;
        if (valid)
            c = (mean * ps - 0.01f * logf(ps)) * (1.0f / (NV * BS));
        atomicAdd(acc, c);
    }
}

__global__ void finalize_kernel(const float* __restrict__ acc, float* __restrict__ out) {
    float vv = acc[0];
    if (isnan(vv) || isinf(vv)) vv = 0.0f;
    out[0] = vv;  // gadd_loss + 0*gadd == gadd_loss (gadd finite)
}

extern "C" void kernel_launch(void* const* d_in, const int* in_sizes, int n_in,
                              void* d_out, int out_size, void* d_ws, size_t ws_size,
                              hipStream_t stream) {
    const float* pred_r     = (const float*)d_in[0];
    const float* pred_t     = (const float*)d_in[1];
    const float* pred_score = (const float*)d_in[2];
    const float* gt_r       = (const float*)d_in[3];
    const float* gt_t       = (const float*)d_in[4];
    const int*   cls_ids    = (const int*)d_in[5];
    const float* model_xyz  = (const float*)d_in[6];
    float* out = (float*)d_out;
    float* acc = (float*)d_ws;   // 1 float accumulator (poisoned 0xAA -> must zero)

    zero_acc_kernel<<<1, 1, 0, stream>>>(acc);
    dim3 grid(NV, BS);
    get_loss_kernel<<<grid, 256, 0, stream>>>(pred_r, pred_t, pred_score,
                                              gt_r, gt_t, cls_ids, model_xyz, acc);
    finalize_kernel<<<1, 1, 0, stream>>>(acc, out);
}

// Round 2
// 71.744 us; speedup vs baseline: 1.2667x; 1.2667x over previous
//
#include <hip/hip_runtime.h>
#include <math.h>

#define NP 400
#define NV 204
#define STEP 20
#define HW 4096
#define BS 8
#define NBLK (NV * BS)   // 1632 partials

// One block per (b, v). 512 threads; threads 0..399 each own one model point.
__global__ __launch_bounds__(512) void partial_kernel(
    const float* __restrict__ pred_r,    // (8,4,4096)
    const float* __restrict__ pred_t,    // (8,3,4096)
    const float* __restrict__ pred_score,// (8,4096)
    const float* __restrict__ gt_r,      // (8,3,3)
    const float* __restrict__ gt_t,      // (8,3)
    const int*   __restrict__ cls_ids,   // (8,)
    const float* __restrict__ model_xyz, // (8,3,400)
    float* __restrict__ partials)        // (1632,)
{
    const int v   = blockIdx.x;   // 0..203
    const int b   = blockIdx.y;   // 0..7
    const int tid = threadIdx.x;  // 0..511
    const int pix = v * STEP;

    __shared__ float4 s_g[NP];    // gt-transformed points (x,y,z,0)
    __shared__ float  s_part[8];

    const int   cls = cls_ids[b];
    const bool  sym = (cls==12)||(cls==15)||(cls==18)||(cls==19)||(cls==20);
    const bool  valid = (cls+1 >= 1) && (cls+1 <= 30); // SELECT_ID = 1..30 (always true here)

    const float* mb = model_xyz + (size_t)b * 3 * NP;

    // ---- stage gt points in LDS (one point per thread) ----
    if (tid < NP) {
        const float g00 = gt_r[b*9+0], g01 = gt_r[b*9+1], g02 = gt_r[b*9+2];
        const float g10 = gt_r[b*9+3], g11 = gt_r[b*9+4], g12 = gt_r[b*9+5];
        const float g20 = gt_r[b*9+6], g21 = gt_r[b*9+7], g22 = gt_r[b*9+8];
        const float gtx = gt_t[b*3+0], gty = gt_t[b*3+1], gtz = gt_t[b*3+2];
        float mx = mb[tid], my = mb[NP+tid], mz = mb[2*NP+tid];
        s_g[tid] = make_float4(g00*mx + g01*my + g02*mz + gtx,
                               g10*mx + g11*my + g12*mz + gty,
                               g20*mx + g21*my + g22*mz + gtz, 0.0f);
    }

    // ---- quaternion -> rotation (uniform per block) ----
    float q0 = pred_r[((size_t)b*4+0)*HW + pix];
    float q1 = pred_r[((size_t)b*4+1)*HW + pix];
    float q2 = pred_r[((size_t)b*4+2)*HW + pix];
    float q3 = pred_r[((size_t)b*4+3)*HW + pix];
    {
        float inv = 1.0f / sqrtf(q0*q0 + q1*q1 + q2*q2 + q3*q3);
        q0 *= inv; q1 *= inv; q2 *= inv; q3 *= inv;
    }
    const float R00 = 1.0f - 2.0f*(q2*q2 + q3*q3);
    const float R01 = 2.0f*q1*q2 - 2.0f*q0*q3;
    const float R02 = 2.0f*q0*q2 + 2.0f*q1*q3;
    const float R10 = 2.0f*q1*q2 + 2.0f*q3*q0;
    const float R11 = 1.0f - 2.0f*(q1*q1 + q3*q3);
    const float R12 = -2.0f*q0*q1 + 2.0f*q2*q3;
    const float R20 = -2.0f*q0*q2 + 2.0f*q1*q3;
    const float R21 = 2.0f*q0*q1 + 2.0f*q2*q3;
    const float R22 = 1.0f - 2.0f*(q1*q1 + q2*q2);

    const float ptx = pred_t[((size_t)b*3+0)*HW + pix];
    const float pty = pred_t[((size_t)b*3+1)*HW + pix];
    const float ptz = pred_t[((size_t)b*3+2)*HW + pix];

    __syncthreads();

    // ---- per-point distance ----
    float local = 0.0f;
    if (tid < NP) {
        const int p = tid;
        float mx = mb[p], my = mb[NP+p], mz = mb[2*NP+p];
        float px = R00*mx + R01*my + R02*mz + ptx;
        float py = R10*mx + R11*my + R12*mz + pty;
        float pz = R20*mx + R21*my + R22*mz + ptz;
        float d2;
        if (sym) {
            // ADD-S: min_q ||p-g_q||^2. LDS reads wave-uniform -> broadcast.
            // 4 independent min chains break the fminf latency dependency.
            float m0 = 3.4e38f, m1 = 3.4e38f, m2 = 3.4e38f, m3 = 3.4e38f;
            for (int q = 0; q < NP; q += 4) {
                float4 g0 = s_g[q+0], g1 = s_g[q+1], g2 = s_g[q+2], g3 = s_g[q+3];
                float dx0 = px-g0.x, dy0 = py-g0.y, dz0 = pz-g0.z;
                float dx1 = px-g1.x, dy1 = py-g1.y, dz1 = pz-g1.z;
                float dx2 = px-g2.x, dy2 = py-g2.y, dz2 = pz-g2.z;
                float dx3 = px-g3.x, dy3 = py-g3.y, dz3 = pz-g3.z;
                m0 = fminf(m0, dx0*dx0 + dy0*dy0 + dz0*dz0);
                m1 = fminf(m1, dx1*dx1 + dy1*dy1 + dz1*dz1);
                m2 = fminf(m2, dx2*dx2 + dy2*dy2 + dz2*dz2);
                m3 = fminf(m3, dx3*dx3 + dy3*dy3 + dz3*dz3);
            }
            d2 = fminf(fminf(m0, m1), fminf(m2, m3));
        } else {
            float4 g = s_g[p];
            float dx = px-g.x, dy = py-g.y, dz = pz-g.z;
            d2 = dx*dx + dy*dy + dz*dz;
        }
        local = sqrtf(d2);
    }

    // ---- block reduction (8 waves of 64) ----
    #pragma unroll
    for (int off = 32; off > 0; off >>= 1)
        local += __shfl_down(local, off, 64);
    const int wave = tid >> 6;
    if ((tid & 63) == 0) s_part[wave] = local;
    __syncthreads();
    if (tid == 0) {
        float tot = 0.0f;
        #pragma unroll
        for (int w = 0; w < 8; ++w) tot += s_part[w];
        float mean = tot * (1.0f / NP);                 // add_ij[b,v]
        float ps   = pred_score[(size_t)b*HW + pix];
        float c = 0.0f;
        if (valid)
            c = (mean * ps - 0.01f * logf(ps)) * (1.0f / NBLK);
        partials[b * NV + v] = c;   // unconditional write: no init needed
    }
}

__global__ __launch_bounds__(256) void finalize_kernel(
    const float* __restrict__ partials, float* __restrict__ out)
{
    __shared__ float s_part[4];
    const int tid = threadIdx.x;
    float local = 0.0f;
    for (int i = tid; i < NBLK; i += 256) local += partials[i];
    #pragma unroll
    for (int off = 32; off > 0; off >>= 1)
        local += __shfl_down(local, off, 64);
    if ((tid & 63) == 0) s_part[tid >> 6] = local;
    __syncthreads();
    if (tid == 0) {
        float vv = s_part[0] + s_part[1] + s_part[2] + s_part[3];
        if (isnan(vv) || isinf(vv)) vv = 0.0f;
        out[0] = vv;   // gadd_loss + 0*gadd == gadd_loss
    }
}

extern "C" void kernel_launch(void* const* d_in, const int* in_sizes, int n_in,
                              void* d_out, int out_size, void* d_ws, size_t ws_size,
                              hipStream_t stream) {
    const float* pred_r     = (const float*)d_in[0];
    const float* pred_t     = (const float*)d_in[1];
    const float* pred_score = (const float*)d_in[2];
    const float* gt_r       = (const float*)d_in[3];
    const float* gt_t       = (const float*)d_in[4];
    const int*   cls_ids    = (const int*)d_in[5];
    const float* model_xyz  = (const float*)d_in[6];
    float* out      = (float*)d_out;
    float* partials = (float*)d_ws;  // 1632 floats, fully overwritten each call

    dim3 grid(NV, BS);
    partial_kernel<<<grid, 512, 0, stream>>>(pred_r, pred_t, pred_score,
                                             gt_r, gt_t, cls_ids, model_xyz, partials);
    finalize_kernel<<<1, 256, 0, stream>>>(partials, out);
}

// Round 3
// 69.989 us; speedup vs baseline: 1.2985x; 1.0251x over previous
//
#include <hip/hip_runtime.h>
#include <math.h>

#define NP 400
#define NV 204
#define STEP 20
#define HW 4096
#define BS 8
#define NBLK (NV * BS)   // 1632 partials

// One block per (b, v). 256 threads (4 waves => all 1632 blocks co-resident:
// 6528 waves < 8192 device capacity). Thread t owns p = t and p = t+256 (t<144).
__global__ __launch_bounds__(256) void partial_kernel(
    const float* __restrict__ pred_r,    // (8,4,4096)
    const float* __restrict__ pred_t,    // (8,3,4096)
    const float* __restrict__ pred_score,// (8,4096)
    const float* __restrict__ gt_r,      // (8,3,3)
    const float* __restrict__ gt_t,      // (8,3)
    const int*   __restrict__ cls_ids,   // (8,)
    const float* __restrict__ model_xyz, // (8,3,400)
    float* __restrict__ partials)        // (1632,)
{
    const int v   = blockIdx.x;   // 0..203
    const int b   = blockIdx.y;   // 0..7
    const int tid = threadIdx.x;  // 0..255
    const int pix = v * STEP;

    // SoA so a ds_read_b128 fetches 4 consecutive q's of one coordinate.
    __shared__ float s_gx[NP], s_gy[NP], s_gz[NP];
    __shared__ float s_part[4];

    const int   cls = cls_ids[b];
    const bool  sym = (cls==12)||(cls==15)||(cls==18)||(cls==19)||(cls==20);
    const bool  valid = (cls+1 >= 1) && (cls+1 <= 30); // SELECT_ID = 1..30 (always true here)
    const bool  has2 = (tid < NP - 256);               // tid < 144

    const float* mb = model_xyz + (size_t)b * 3 * NP;

    // ---- stage gt-transformed points in LDS ----
    {
        const float g00 = gt_r[b*9+0], g01 = gt_r[b*9+1], g02 = gt_r[b*9+2];
        const float g10 = gt_r[b*9+3], g11 = gt_r[b*9+4], g12 = gt_r[b*9+5];
        const float g20 = gt_r[b*9+6], g21 = gt_r[b*9+7], g22 = gt_r[b*9+8];
        const float gtx = gt_t[b*3+0], gty = gt_t[b*3+1], gtz = gt_t[b*3+2];
        for (int q = tid; q < NP; q += 256) {
            float mx = mb[q], my = mb[NP+q], mz = mb[2*NP+q];
            s_gx[q] = g00*mx + g01*my + g02*mz + gtx;
            s_gy[q] = g10*mx + g11*my + g12*mz + gty;
            s_gz[q] = g20*mx + g21*my + g22*mz + gtz;
        }
    }

    // ---- quaternion -> rotation (uniform per block) ----
    float q0 = pred_r[((size_t)b*4+0)*HW + pix];
    float q1 = pred_r[((size_t)b*4+1)*HW + pix];
    float q2 = pred_r[((size_t)b*4+2)*HW + pix];
    float q3 = pred_r[((size_t)b*4+3)*HW + pix];
    {
        float inv = 1.0f / sqrtf(q0*q0 + q1*q1 + q2*q2 + q3*q3);
        q0 *= inv; q1 *= inv; q2 *= inv; q3 *= inv;
    }
    const float R00 = 1.0f - 2.0f*(q2*q2 + q3*q3);
    const float R01 = 2.0f*q1*q2 - 2.0f*q0*q3;
    const float R02 = 2.0f*q0*q2 + 2.0f*q1*q3;
    const float R10 = 2.0f*q1*q2 + 2.0f*q3*q0;
    const float R11 = 1.0f - 2.0f*(q1*q1 + q3*q3);
    const float R12 = -2.0f*q0*q1 + 2.0f*q2*q3;
    const float R20 = -2.0f*q0*q2 + 2.0f*q1*q3;
    const float R21 = 2.0f*q0*q1 + 2.0f*q2*q3;
    const float R22 = 1.0f - 2.0f*(q1*q1 + q2*q2);

    const float ptx = pred_t[((size_t)b*3+0)*HW + pix];
    const float pty = pred_t[((size_t)b*3+1)*HW + pix];
    const float ptz = pred_t[((size_t)b*3+2)*HW + pix];

    __syncthreads();

    // ---- predicted points for this thread's two p's ----
    const int p0 = tid;
    const int p1 = has2 ? tid + 256 : tid;  // dup p0 when absent; discarded below
    float mx0 = mb[p0], my0 = mb[NP+p0], mz0 = mb[2*NP+p0];
    float mx1 = mb[p1], my1 = mb[NP+p1], mz1 = mb[2*NP+p1];
    const float px0 = R00*mx0 + R01*my0 + R02*mz0 + ptx;
    const float py0 = R10*mx0 + R11*my0 + R12*mz0 + pty;
    const float pz0 = R20*mx0 + R21*my0 + R22*mz0 + ptz;
    const float px1 = R00*mx1 + R01*my1 + R02*mz1 + ptx;
    const float py1 = R10*mx1 + R11*my1 + R12*mz1 + pty;
    const float pz1 = R20*mx1 + R21*my1 + R22*mz1 + ptz;

    float d2_0, d2_1;
    if (sym) {
        // ADD-S: min_q ||p-g_q||^2. Uniform-address LDS reads (broadcast),
        // 4 q's per ds_read_b128, 4 independent min chains per p.
        float a0 = 3.4e38f, a1 = 3.4e38f, a2 = 3.4e38f, a3 = 3.4e38f;
        float b0 = 3.4e38f, b1 = 3.4e38f, b2 = 3.4e38f, b3 = 3.4e38f;
        for (int q = 0; q < NP; q += 4) {
            const float4 gx = *reinterpret_cast<const float4*>(&s_gx[q]);
            const float4 gy = *reinterpret_cast<const float4*>(&s_gy[q]);
            const float4 gz = *reinterpret_cast<const float4*>(&s_gz[q]);
            {
                float dx = px0-gx.x, dy = py0-gy.x, dz = pz0-gz.x;
                a0 = fminf(a0, dx*dx + dy*dy + dz*dz);
                dx = px0-gx.y; dy = py0-gy.y; dz = pz0-gz.y;
                a1 = fminf(a1, dx*dx + dy*dy + dz*dz);
                dx = px0-gx.z; dy = py0-gy.z; dz = pz0-gz.z;
                a2 = fminf(a2, dx*dx + dy*dy + dz*dz);
                dx = px0-gx.w; dy = py0-gy.w; dz = pz0-gz.w;
                a3 = fminf(a3, dx*dx + dy*dy + dz*dz);
            }
            {
                float dx = px1-gx.x, dy = py1-gy.x, dz = pz1-gz.x;
                b0 = fminf(b0, dx*dx + dy*dy + dz*dz);
                dx = px1-gx.y; dy = py1-gy.y; dz = pz1-gz.y;
                b1 = fminf(b1, dx*dx + dy*dy + dz*dz);
                dx = px1-gx.z; dy = py1-gy.z; dz = pz1-gz.z;
                b2 = fminf(b2, dx*dx + dy*dy + dz*dz);
                dx = px1-gx.w; dy = py1-gy.w; dz = pz1-gz.w;
                b3 = fminf(b3, dx*dx + dy*dy + dz*dz);
            }
        }
        d2_0 = fminf(fminf(a0, a1), fminf(a2, a3));
        d2_1 = fminf(fminf(b0, b1), fminf(b2, b3));
    } else {
        float dx = px0 - s_gx[p0], dy = py0 - s_gy[p0], dz = pz0 - s_gz[p0];
        d2_0 = dx*dx + dy*dy + dz*dz;
        dx = px1 - s_gx[p1]; dy = py1 - s_gy[p1]; dz = pz1 - s_gz[p1];
        d2_1 = dx*dx + dy*dy + dz*dz;
    }
    float local = sqrtf(d2_0) + (has2 ? sqrtf(d2_1) : 0.0f);

    // ---- block reduction (4 waves of 64) ----
    #pragma unroll
    for (int off = 32; off > 0; off >>= 1)
        local += __shfl_down(local, off, 64);
    const int wave = tid >> 6;
    if ((tid & 63) == 0) s_part[wave] = local;
    __syncthreads();
    if (tid == 0) {
        float tot  = s_part[0] + s_part[1] + s_part[2] + s_part[3];
        float mean = tot * (1.0f / NP);                 // add_ij[b,v]
        float ps   = pred_score[(size_t)b*HW + pix];
        float c = 0.0f;
        if (valid)
            c = (mean * ps - 0.01f * logf(ps)) * (1.0f / NBLK);
        partials[b * NV + v] = c;   // unconditional write: no init needed
    }
}

__global__ __launch_bounds__(256) void finalize_kernel(
    const float* __restrict__ partials, float* __restrict__ out)
{
    __shared__ float s_part[4];
    const int tid = threadIdx.x;
    const float4* p4 = reinterpret_cast<const float4*>(partials);
    float local = 0.0f;
    for (int i = tid; i < NBLK / 4; i += 256) {   // 408 float4's
        float4 vv = p4[i];
        local += vv.x + vv.y + vv.z + vv.w;
    }
    #pragma unroll
    for (int off = 32; off > 0; off >>= 1)
        local += __shfl_down(local, off, 64);
    if ((tid & 63) == 0) s_part[tid >> 6] = local;
    __syncthreads();
    if (tid == 0) {
        float vv = s_part[0] + s_part[1] + s_part[2] + s_part[3];
        if (isnan(vv) || isinf(vv)) vv = 0.0f;
        out[0] = vv;   // gadd_loss + 0*gadd == gadd_loss
    }
}

extern "C" void kernel_launch(void* const* d_in, const int* in_sizes, int n_in,
                              void* d_out, int out_size, void* d_ws, size_t ws_size,
                              hipStream_t stream) {
    const float* pred_r     = (const float*)d_in[0];
    const float* pred_t     = (const float*)d_in[1];
    const float* pred_score = (const float*)d_in[2];
    const float* gt_r       = (const float*)d_in[3];
    const float* gt_t       = (const float*)d_in[4];
    const int*   cls_ids    = (const int*)d_in[5];
    const float* model_xyz  = (const float*)d_in[6];
    float* out      = (float*)d_out;
    float* partials = (float*)d_ws;  // 1632 floats, fully overwritten each call

    dim3 grid(NV, BS);
    partial_kernel<<<grid, 256, 0, stream>>>(pred_r, pred_t, pred_score,
                                             gt_r, gt_t, cls_ids, model_xyz, partials);
    finalize_kernel<<<1, 256, 0, stream>>>(partials, out);
}

// Round 4
// 69.711 us; speedup vs baseline: 1.3036x; 1.0040x over previous
//
#include <hip/hip_runtime.h>
#include <math.h>

#define NP 400
#define NV 204
#define STEP 20
#define HW 4096
#define BS 8
#define NBLK (NV * BS)   // 1632 partials

// One block per (b, v). 256 threads / 4 waves => 6528 waves, all co-resident.
// Thread t owns p = t, and p = t+256 when t < 144.
// ADD-S inner loop uses the reference's d2 = pn + gn - 2*dot expansion:
// LDS holds (gx,gy,gz,gn) per q; per (p,q) cost = 3 FMA + 1 min = 4 VALU ops
// (vs 7 for the direct-difference form). pn is added once after the min.
__global__ __launch_bounds__(256) void partial_kernel(
    const float* __restrict__ pred_r,    // (8,4,4096)
    const float* __restrict__ pred_t,    // (8,3,4096)
    const float* __restrict__ pred_score,// (8,4096)
    const float* __restrict__ gt_r,      // (8,3,3)
    const float* __restrict__ gt_t,      // (8,3)
    const int*   __restrict__ cls_ids,   // (8,)
    const float* __restrict__ model_xyz, // (8,3,400)
    float* __restrict__ partials)        // (1632,)
{
    const int v   = blockIdx.x;   // 0..203
    const int b   = blockIdx.y;   // 0..7
    const int tid = threadIdx.x;  // 0..255
    const int pix = v * STEP;

    __shared__ float4 s_g[NP];    // (gx, gy, gz, gn) per gt point
    __shared__ float  s_part[4];

    const int   cls = cls_ids[b];
    const bool  sym = (cls==12)||(cls==15)||(cls==18)||(cls==19)||(cls==20);
    const bool  valid = (cls+1 >= 1) && (cls+1 <= 30); // SELECT_ID = 1..30 (always true here)
    const bool  has2 = (tid < NP - 256);               // tid < 144

    const float* mb = model_xyz + (size_t)b * 3 * NP;

    // ---- stage gt-transformed points (+ squared norm) in LDS ----
    {
        const float g00 = gt_r[b*9+0], g01 = gt_r[b*9+1], g02 = gt_r[b*9+2];
        const float g10 = gt_r[b*9+3], g11 = gt_r[b*9+4], g12 = gt_r[b*9+5];
        const float g20 = gt_r[b*9+6], g21 = gt_r[b*9+7], g22 = gt_r[b*9+8];
        const float gtx = gt_t[b*3+0], gty = gt_t[b*3+1], gtz = gt_t[b*3+2];
        for (int q = tid; q < NP; q += 256) {
            float mx = mb[q], my = mb[NP+q], mz = mb[2*NP+q];
            float gx = g00*mx + g01*my + g02*mz + gtx;
            float gy = g10*mx + g11*my + g12*mz + gty;
            float gz = g20*mx + g21*my + g22*mz + gtz;
            s_g[q] = make_float4(gx, gy, gz, gx*gx + gy*gy + gz*gz);
        }
    }

    // ---- quaternion -> rotation (uniform per block) ----
    float q0 = pred_r[((size_t)b*4+0)*HW + pix];
    float q1 = pred_r[((size_t)b*4+1)*HW + pix];
    float q2 = pred_r[((size_t)b*4+2)*HW + pix];
    float q3 = pred_r[((size_t)b*4+3)*HW + pix];
    {
        float inv = 1.0f / sqrtf(q0*q0 + q1*q1 + q2*q2 + q3*q3);
        q0 *= inv; q1 *= inv; q2 *= inv; q3 *= inv;
    }
    const float R00 = 1.0f - 2.0f*(q2*q2 + q3*q3);
    const float R01 = 2.0f*q1*q2 - 2.0f*q0*q3;
    const float R02 = 2.0f*q0*q2 + 2.0f*q1*q3;
    const float R10 = 2.0f*q1*q2 + 2.0f*q3*q0;
    const float R11 = 1.0f - 2.0f*(q1*q1 + q3*q3);
    const float R12 = -2.0f*q0*q1 + 2.0f*q2*q3;
    const float R20 = -2.0f*q0*q2 + 2.0f*q1*q3;
    const float R21 = 2.0f*q0*q1 + 2.0f*q2*q3;
    const float R22 = 1.0f - 2.0f*(q1*q1 + q2*q2);

    const float ptx = pred_t[((size_t)b*3+0)*HW + pix];
    const float pty = pred_t[((size_t)b*3+1)*HW + pix];
    const float ptz = pred_t[((size_t)b*3+2)*HW + pix];

    __syncthreads();

    // ---- predicted points for this thread's p's ----
    const int p0 = tid;
    const int p1 = has2 ? tid + 256 : tid;
    float mx0 = mb[p0], my0 = mb[NP+p0], mz0 = mb[2*NP+p0];
    float mx1 = mb[p1], my1 = mb[NP+p1], mz1 = mb[2*NP+p1];
    const float px0 = R00*mx0 + R01*my0 + R02*mz0 + ptx;
    const float py0 = R10*mx0 + R11*my0 + R12*mz0 + pty;
    const float pz0 = R20*mx0 + R21*my0 + R22*mz0 + ptz;
    const float px1 = R00*mx1 + R01*my1 + R02*mz1 + ptx;
    const float py1 = R10*mx1 + R11*my1 + R12*mz1 + pty;
    const float pz1 = R20*mx1 + R21*my1 + R22*mz1 + ptz;

    float d2_0 = 0.0f, d2_1 = 0.0f;
    if (sym) {
        const float nx0 = -2.0f*px0, ny0 = -2.0f*py0, nz0 = -2.0f*pz0;
        const float pn0 = px0*px0 + py0*py0 + pz0*pz0;
        if (tid < 192) {
            // waves 0..2: two points per thread (lanes 144..191 compute a dup)
            const float nx1 = -2.0f*px1, ny1 = -2.0f*py1, nz1 = -2.0f*pz1;
            const float pn1 = px1*px1 + py1*py1 + pz1*pz1;
            float a0 = 3.4e38f, a1 = 3.4e38f, a2 = 3.4e38f, a3 = 3.4e38f;
            float c0 = 3.4e38f, c1 = 3.4e38f, c2 = 3.4e38f, c3 = 3.4e38f;
            for (int q = 0; q < NP; q += 4) {
                const float4 g0 = s_g[q+0], g1 = s_g[q+1];
                const float4 g2 = s_g[q+2], g3 = s_g[q+3];
                a0 = fminf(a0, fmaf(nx0, g0.x, fmaf(ny0, g0.y, fmaf(nz0, g0.z, g0.w))));
                a1 = fminf(a1, fmaf(nx0, g1.x, fmaf(ny0, g1.y, fmaf(nz0, g1.z, g1.w))));
                a2 = fminf(a2, fmaf(nx0, g2.x, fmaf(ny0, g2.y, fmaf(nz0, g2.z, g2.w))));
                a3 = fminf(a3, fmaf(nx0, g3.x, fmaf(ny0, g3.y, fmaf(nz0, g3.z, g3.w))));
                c0 = fminf(c0, fmaf(nx1, g0.x, fmaf(ny1, g0.y, fmaf(nz1, g0.z, g0.w))));
                c1 = fminf(c1, fmaf(nx1, g1.x, fmaf(ny1, g1.y, fmaf(nz1, g1.z, g1.w))));
                c2 = fminf(c2, fmaf(nx1, g2.x, fmaf(ny1, g2.y, fmaf(nz1, g2.z, g2.w))));
                c3 = fminf(c3, fmaf(nx1, g3.x, fmaf(ny1, g3.y, fmaf(nz1, g3.z, g3.w))));
            }
            d2_0 = fmaxf(pn0 + fminf(fminf(a0, a1), fminf(a2, a3)), 0.0f);
            d2_1 = fmaxf(pn1 + fminf(fminf(c0, c1), fminf(c2, c3)), 0.0f);
        } else {
            // wave 3: single point per thread — half the work
            float a0 = 3.4e38f, a1 = 3.4e38f, a2 = 3.4e38f, a3 = 3.4e38f;
            for (int q = 0; q < NP; q += 4) {
                const float4 g0 = s_g[q+0], g1 = s_g[q+1];
                const float4 g2 = s_g[q+2], g3 = s_g[q+3];
                a0 = fminf(a0, fmaf(nx0, g0.x, fmaf(ny0, g0.y, fmaf(nz0, g0.z, g0.w))));
                a1 = fminf(a1, fmaf(nx0, g1.x, fmaf(ny0, g1.y, fmaf(nz0, g1.z, g1.w))));
                a2 = fminf(a2, fmaf(nx0, g2.x, fmaf(ny0, g2.y, fmaf(nz0, g2.z, g2.w))));
                a3 = fminf(a3, fmaf(nx0, g3.x, fmaf(ny0, g3.y, fmaf(nz0, g3.z, g3.w))));
            }
            d2_0 = fmaxf(pn0 + fminf(fminf(a0, a1), fminf(a2, a3)), 0.0f);
            d2_1 = 0.0f;
        }
    } else {
        // ADD path: reference uses direct differences
        float4 g = s_g[p0];
        float dx = px0 - g.x, dy = py0 - g.y, dz = pz0 - g.z;
        d2_0 = dx*dx + dy*dy + dz*dz;
        g = s_g[p1];
        dx = px1 - g.x; dy = py1 - g.y; dz = pz1 - g.z;
        d2_1 = dx*dx + dy*dy + dz*dz;
    }
    float local = sqrtf(d2_0) + (has2 ? sqrtf(d2_1) : 0.0f);

    // ---- block reduction (4 waves of 64) ----
    #pragma unroll
    for (int off = 32; off > 0; off >>= 1)
        local += __shfl_down(local, off, 64);
    const int wave = tid >> 6;
    if ((tid & 63) == 0) s_part[wave] = local;
    __syncthreads();
    if (tid == 0) {
        float tot  = s_part[0] + s_part[1] + s_part[2] + s_part[3];
        float mean = tot * (1.0f / NP);                 // add_ij[b,v]
        float ps   = pred_score[(size_t)b*HW + pix];
        float c = 0.0f;
        if (valid)
            c = (mean * ps - 0.01f * logf(ps)) * (1.0f / NBLK);
        partials[b * NV + v] = c;   // unconditional write: no init needed
    }
}

__global__ __launch_bounds__(256) void finalize_kernel(
    const float* __restrict__ partials, float* __restrict__ out)
{
    __shared__ float s_part[4];
    const int tid = threadIdx.x;
    const float4* p4 = reinterpret_cast<const float4*>(partials);
    float local = 0.0f;
    for (int i = tid; i < NBLK / 4; i += 256) {   // 408 float4's
        float4 vv = p4[i];
        local += vv.x + vv.y + vv.z + vv.w;
    }
    #pragma unroll
    for (int off = 32; off > 0; off >>= 1)
        local += __shfl_down(local, off, 64);
    if ((tid & 63) == 0) s_part[tid >> 6] = local;
    __syncthreads();
    if (tid == 0) {
        float vv = s_part[0] + s_part[1] + s_part[2] + s_part[3];
        if (isnan(vv) || isinf(vv)) vv = 0.0f;
        out[0] = vv;   // gadd_loss + 0*gadd == gadd_loss
    }
}

extern "C" void kernel_launch(void* const* d_in, const int* in_sizes, int n_in,
                              void* d_out, int out_size, void* d_ws, size_t ws_size,
                              hipStream_t stream) {
    const float* pred_r     = (const float*)d_in[0];
    const float* pred_t     = (const float*)d_in[1];
    const float* pred_score = (const float*)d_in[2];
    const float* gt_r       = (const float*)d_in[3];
    const float* gt_t       = (const float*)d_in[4];
    const int*   cls_ids    = (const int*)d_in[5];
    const float* model_xyz  = (const float*)d_in[6];
    float* out      = (float*)d_out;
    float* partials = (float*)d_ws;  // 1632 floats, fully overwritten each call

    dim3 grid(NV, BS);
    partial_kernel<<<grid, 256, 0, stream>>>(pred_r, pred_t, pred_score,
                                             gt_r, gt_t, cls_ids, model_xyz, partials);
    finalize_kernel<<<1, 256, 0, stream>>>(partials, out);
}